// Round 11
// baseline (369.385 us; speedup 1.0000x reference)
//
#include <hip/hip_runtime.h>
#include <math.h>

// Problem constants: N=100000, E=3200000, F=256, H=32, C=16
constexpr int Fdim = 256;
constexpr int Hdim = 32;
constexpr int Cdim = 16;
constexpr int EPB = 8192;   // edges per block in pass B
constexpr int MAXNB = 512;  // max coarse buckets (N <= 131072)

// ---- bf16 helpers (RNE) ----
__device__ inline unsigned bfpack2(float lo, float hi) {
  unsigned a = __builtin_bit_cast(unsigned, lo);
  unsigned b = __builtin_bit_cast(unsigned, hi);
  a += 0x7FFFu + ((a >> 16) & 1u);
  b += 0x7FFFu + ((b >> 16) & 1u);
  return (a >> 16) | (b & 0xFFFF0000u);
}
__device__ inline float4 bfunpack4(uint2 w) {
  float4 r;
  r.x = __builtin_bit_cast(float, w.x << 16);
  r.y = __builtin_bit_cast(float, w.x & 0xFFFF0000u);
  r.z = __builtin_bit_cast(float, w.y << 16);
  r.w = __builtin_bit_cast(float, w.y & 0xFFFF0000u);
  return r;
}

__global__ __launch_bounds__(256) void k_zero_int(int* __restrict__ p, int n) {
  int i = blockIdx.x * blockDim.x + threadIdx.x;
  if (i < n) p[i] = 0;
}

// ---------- Pass B: coarse-bin edges by dst>>8 into bucket-contiguous chunks.
__global__ __launch_bounds__(256) void k_binB(const int* __restrict__ src,
                                              const int* __restrict__ dst,
                                              int* __restrict__ bcur,
                                              unsigned* __restrict__ pairs,
                                              int e, int nb, int bcap) {
  __shared__ int hist[MAXNB];
  __shared__ int cbase[MAXNB];
  int lo = blockIdx.x * EPB;
  int hi = lo + EPB;
  if (hi > e) hi = e;
  for (int t = threadIdx.x; t < nb; t += 256) hist[t] = 0;
  __syncthreads();
  for (int i = lo + threadIdx.x; i < hi; i += 256) {
    atomicAdd(&hist[dst[i] >> 8], 1);
  }
  __syncthreads();
  for (int t = threadIdx.x; t < nb; t += 256) {
    int h = hist[t];
    int base = h ? atomicAdd(&bcur[t], h) : 0;
    cbase[t] = t * bcap + base;
    hist[t] = 0;  // reuse as local cursor
  }
  __syncthreads();
  for (int i = lo + threadIdx.x; i < hi; i += 256) {
    int d = dst[i];
    int bk = d >> 8;
    int o = atomicAdd(&hist[bk], 1);
    int idx = cbase[bk] + o;
    if (idx < (bk + 1) * bcap)  // statistical overflow guard
      pairs[idx] = ((unsigned)(d & 255) << 24) | (unsigned)src[i];
  }
}

// ---------- exclusive scan of bucket counts -> packed-CSR bucket bases ----------
__global__ __launch_bounds__(512) void k_scanb(const int* __restrict__ bcur,
                                               int* __restrict__ bbase,
                                               int nb, int bcap) {
  __shared__ int s[512];
  int t = threadIdx.x;
  int v = 0;
  if (t < nb) {
    v = bcur[t];
    if (v > bcap) v = bcap;
  }
  s[t] = v;
  __syncthreads();
  for (int off = 1; off < 512; off <<= 1) {
    int u = (t >= off) ? s[t - off] : 0;
    __syncthreads();
    s[t] += u;
    __syncthreads();
  }
  if (t < nb) bbase[t] = s[t] - v;  // exclusive
}

// ---------- Pass C: one block per bucket; LDS counters + LDS scan -> PACKED csr.
__global__ __launch_bounds__(256) void k_binC(const int* __restrict__ bcur,
                                              const int* __restrict__ bbase,
                                              const unsigned* __restrict__ pairs,
                                              int* __restrict__ csr,
                                              int* __restrict__ rowptr,
                                              int* __restrict__ cntg,
                                              float* __restrict__ dinv,
                                              int n, int bcap) {
  __shared__ int cnt2[256];
  __shared__ int loc0[256];
  __shared__ int cur2[256];
  int b = blockIdx.x;
  int tid = threadIdx.x;
  int nE = bcur[b];
  if (nE > bcap) nE = bcap;
  int base = b * bcap;
  cnt2[tid] = 0;
  __syncthreads();
  for (int i = tid; i < nE; i += 256) {
    atomicAdd(&cnt2[pairs[base + i] >> 24], 1);
  }
  __syncthreads();
  int c = cnt2[tid];
  loc0[tid] = c;
  __syncthreads();
  for (int off = 1; off < 256; off <<= 1) {
    int u = (tid >= off) ? loc0[tid - off] : 0;
    __syncthreads();
    loc0[tid] += u;
    __syncthreads();
  }
  int rowstart = bbase[b] + loc0[tid] - c;
  __syncthreads();
  loc0[tid] = rowstart;
  cur2[tid] = 0;
  int d = b * 256 + tid;
  if (d < n) {
    rowptr[d] = rowstart;
    cntg[d] = c;
    dinv[d] = 1.0f / sqrtf((float)(c + 1));  // +1 self-loop
  }
  __syncthreads();
  for (int i = tid; i < nE; i += 256) {
    unsigned w = pairs[base + i];
    int loc = (int)(w >> 24);
    int s = (int)(w & 0xFFFFFFu);
    int o = atomicAdd(&cur2[loc], 1);
    csr[loc0[loc] + o] = s;
  }
}

// ---------- hs1(bf16) = dinv * (x @ W1): thread-per-row (proven 86us form).
__global__ __launch_bounds__(256) void k_lin1(const float4* __restrict__ x4,
                                              const float* __restrict__ W,
                                              const float* __restrict__ dinv,
                                              unsigned short* __restrict__ hs,
                                              int r0, int n) {
  int row = r0 + blockIdx.x * blockDim.x + threadIdx.x;
  if (row >= n) return;
  float acc[Hdim];
#pragma unroll
  for (int c = 0; c < Hdim; ++c) acc[c] = 0.f;
  const float4* xr = x4 + (size_t)row * (Fdim / 4);
#pragma unroll 1
  for (int k4 = 0; k4 < Fdim / 4; ++k4) {
    float4 xv = xr[k4];
    const float* wp = W + k4 * 4 * Hdim;  // block-uniform -> s_load
#pragma unroll
    for (int c = 0; c < Hdim; ++c) acc[c] = fmaf(xv.x, wp[c], acc[c]);
#pragma unroll
    for (int c = 0; c < Hdim; ++c) acc[c] = fmaf(xv.y, wp[Hdim + c], acc[c]);
#pragma unroll
    for (int c = 0; c < Hdim; ++c) acc[c] = fmaf(xv.z, wp[2 * Hdim + c], acc[c]);
#pragma unroll
    for (int c = 0; c < Hdim; ++c) acc[c] = fmaf(xv.w, wp[3 * Hdim + c], acc[c]);
  }
  float di = dinv[row];
  uint4* hp = (uint4*)(hs + (size_t)row * Hdim);  // 64B row, 4x uint4
#pragma unroll
  for (int q = 0; q < 4; ++q) {
    uint4 u;
    u.x = bfpack2(di * acc[8 * q + 0], di * acc[8 * q + 1]);
    u.y = bfpack2(di * acc[8 * q + 2], di * acc[8 * q + 3]);
    u.z = bfpack2(di * acc[8 * q + 4], di * acc[8 * q + 5]);
    u.w = bfpack2(di * acc[8 * q + 6], di * acc[8 * q + 7]);
    hp[q] = u;
  }
}

// ---------- Fused gather1 + relu/bias + lin2: 8 lanes/row, bf16 rows ----------
__global__ __launch_bounds__(256) void k_g1l2(const int* __restrict__ rowptr,
                                              const int* __restrict__ cnt,
                                              const int* __restrict__ csr,
                                              const unsigned short* __restrict__ hs,
                                              const float* __restrict__ dinv,
                                              const float* __restrict__ b1,
                                              const float* __restrict__ W2,
                                              unsigned short* __restrict__ hs2, int n) {
  int t = blockIdx.x * blockDim.x + threadIdx.x;
  int d = t >> 3, f = t & 7;
  if (d >= n) return;
  int c = cnt[d];
  const int* row = csr + rowptr[d];
  // self-loop term: lane f reads bf16 elems [4f,4f+4) of own row
  float4 acc = bfunpack4(((const uint2*)(hs + (size_t)d * Hdim))[f]);
  int k = 0;
  for (; k + 3 < c; k += 4) {
    int s0 = row[k], s1 = row[k + 1], s2 = row[k + 2], s3 = row[k + 3];
    float4 v0 = bfunpack4(((const uint2*)(hs + (size_t)s0 * Hdim))[f]);
    float4 v1 = bfunpack4(((const uint2*)(hs + (size_t)s1 * Hdim))[f]);
    float4 v2 = bfunpack4(((const uint2*)(hs + (size_t)s2 * Hdim))[f]);
    float4 v3 = bfunpack4(((const uint2*)(hs + (size_t)s3 * Hdim))[f]);
    acc.x += (v0.x + v1.x) + (v2.x + v3.x);
    acc.y += (v0.y + v1.y) + (v2.y + v3.y);
    acc.z += (v0.z + v1.z) + (v2.z + v3.z);
    acc.w += (v0.w + v1.w) + (v2.w + v3.w);
  }
  for (; k < c; ++k) {
    float4 v = bfunpack4(((const uint2*)(hs + (size_t)row[k] * Hdim))[f]);
    acc.x += v.x; acc.y += v.y; acc.z += v.z; acc.w += v.w;
  }
  float di = dinv[d];
  float h[4];
  h[0] = fmaxf(fmaf(di, acc.x, b1[4 * f + 0]), 0.f);
  h[1] = fmaxf(fmaf(di, acc.y, b1[4 * f + 1]), 0.f);
  h[2] = fmaxf(fmaf(di, acc.z, b1[4 * f + 2]), 0.f);
  h[3] = fmaxf(fmaf(di, acc.w, b1[4 * f + 3]), 0.f);
  float p[Cdim];
#pragma unroll
  for (int j = 0; j < Cdim; ++j) p[j] = 0.f;
#pragma unroll
  for (int r = 0; r < 4; ++r) {
    const float* w = W2 + (4 * f + r) * Cdim;
#pragma unroll
    for (int j = 0; j < Cdim; ++j) p[j] = fmaf(h[r], w[j], p[j]);
  }
#pragma unroll
  for (int m = 1; m < 8; m <<= 1) {
#pragma unroll
    for (int j = 0; j < Cdim; ++j) p[j] += __shfl_xor(p[j], m, 64);
  }
  if (f < 4) {
    uint2 u;
    u.x = bfpack2(di * p[4 * f + 0], di * p[4 * f + 1]);
    u.y = bfpack2(di * p[4 * f + 2], di * p[4 * f + 3]);
    ((uint2*)(hs2 + (size_t)d * Cdim))[f] = u;  // 32B row
  }
}

// ---------- Fused gather2 + softmax: 4 lanes/row, bf16 rows ----------
__global__ __launch_bounds__(256) void k_g2sm(const int* __restrict__ rowptr,
                                              const int* __restrict__ cnt,
                                              const int* __restrict__ csr,
                                              const unsigned short* __restrict__ hs,
                                              const float* __restrict__ dinv,
                                              const float* __restrict__ b2,
                                              float4* __restrict__ out, int n) {
  int t = blockIdx.x * blockDim.x + threadIdx.x;
  int d = t >> 2, f = t & 3;
  if (d >= n) return;
  int c = cnt[d];
  const int* row = csr + rowptr[d];
  float4 acc = bfunpack4(((const uint2*)(hs + (size_t)d * Cdim))[f]);
  int k = 0;
  for (; k + 3 < c; k += 4) {
    int s0 = row[k], s1 = row[k + 1], s2 = row[k + 2], s3 = row[k + 3];
    float4 v0 = bfunpack4(((const uint2*)(hs + (size_t)s0 * Cdim))[f]);
    float4 v1 = bfunpack4(((const uint2*)(hs + (size_t)s1 * Cdim))[f]);
    float4 v2 = bfunpack4(((const uint2*)(hs + (size_t)s2 * Cdim))[f]);
    float4 v3 = bfunpack4(((const uint2*)(hs + (size_t)s3 * Cdim))[f]);
    acc.x += (v0.x + v1.x) + (v2.x + v3.x);
    acc.y += (v0.y + v1.y) + (v2.y + v3.y);
    acc.z += (v0.z + v1.z) + (v2.z + v3.z);
    acc.w += (v0.w + v1.w) + (v2.w + v3.w);
  }
  for (; k < c; ++k) {
    float4 v = bfunpack4(((const uint2*)(hs + (size_t)row[k] * Cdim))[f]);
    acc.x += v.x; acc.y += v.y; acc.z += v.z; acc.w += v.w;
  }
  float di = dinv[d];
  float v0 = fmaf(di, acc.x, b2[4 * f + 0]);
  float v1 = fmaf(di, acc.y, b2[4 * f + 1]);
  float v2 = fmaf(di, acc.z, b2[4 * f + 2]);
  float v3 = fmaf(di, acc.w, b2[4 * f + 3]);
  float m = fmaxf(fmaxf(v0, v1), fmaxf(v2, v3));
  m = fmaxf(m, __shfl_xor(m, 1, 64));
  m = fmaxf(m, __shfl_xor(m, 2, 64));
  float e0 = expf(v0 - m), e1 = expf(v1 - m), e2 = expf(v2 - m), e3 = expf(v3 - m);
  float s = e0 + e1 + e2 + e3;
  s += __shfl_xor(s, 1, 64);
  s += __shfl_xor(s, 2, 64);
  float inv = 1.f / s;
  float4 o;
  o.x = e0 * inv; o.y = e1 * inv; o.z = e2 * inv; o.w = e3 * inv;
  out[(size_t)d * 4 + f] = o;
}

extern "C" void kernel_launch(void* const* d_in, const int* in_sizes, int n_in,
                              void* d_out, int out_size, void* d_ws, size_t ws_size,
                              hipStream_t stream) {
  const float* x = (const float*)d_in[0];
  const int* ei = (const int*)d_in[1];
  const float* W1 = (const float*)d_in[2];
  const float* b1 = (const float*)d_in[3];
  const float* W2 = (const float*)d_in[4];
  const float* b2 = (const float*)d_in[5];
  float* out = (float*)d_out;

  const int N = in_sizes[0] / Fdim;  // 100000
  const int E = in_sizes[1] / 2;     // 3200000
  const int* srcp = ei;              // edge_index[0]
  const int* dstp = ei + E;          // edge_index[1]

  const int NB = (N + 255) >> 8;            // 391 coarse buckets
  const int mean = (E + NB - 1) / NB;       // ~8184 edges/bucket
  const int BCAP = mean + mean / 16 + 256;  // ~8.5 sigma slack

  // Workspace: bcur | bbase | dinv | cntg | rowptr | csr | region{pairs / hs1+hs2}
  char* ws = (char*)d_ws;
  int* bcur = (int*)ws;      ws += (size_t)MAXNB * 4;
  int* bbase = (int*)ws;     ws += (size_t)MAXNB * 4;
  float* dinv = (float*)ws;  ws += (size_t)N * 4;
  int* cntg = (int*)ws;      ws += (size_t)N * 4;
  int* rowptr = (int*)ws;    ws += (size_t)(N + 4) * 4;
  int* csr = (int*)ws;       ws += (size_t)E * 4;  // 12.8 MB packed
  char* region = ws;         // max(pairs ~14MB, hs1 6.4MB + hs2 3.2MB)
  unsigned* pairs = (unsigned*)region;            // dead after k_binC
  unsigned short* hs1 = (unsigned short*)region;  // aliases pairs
  unsigned short* hs2 = (unsigned short*)(region + (size_t)N * Hdim * 2);

  int nbB = (E + EPB - 1) / EPB;  // 391

  k_zero_int<<<(NB + 255) / 256, 256, 0, stream>>>(bcur, NB);
  k_binB<<<nbB, 256, 0, stream>>>(srcp, dstp, bcur, pairs, E, NB, BCAP);
  k_scanb<<<1, 512, 0, stream>>>(bcur, bbase, NB, BCAP);
  k_binC<<<NB, 256, 0, stream>>>(bcur, bbase, pairs, csr, rowptr, cntg, dinv, N, BCAP);

  // lin1 split into 3 row ranges (same total work; profiler visibility)
  {
    int nb_total = (N + 255) / 256;  // 391
    int nb1 = nb_total / 3;
    int nb2 = nb_total / 3;
    int nb3 = nb_total - nb1 - nb2;
    int r1 = nb1 * 256, r2 = (nb1 + nb2) * 256;
    k_lin1<<<nb1, 256, 0, stream>>>((const float4*)x, W1, dinv, hs1, 0, N);
    k_lin1<<<nb2, 256, 0, stream>>>((const float4*)x, W1, dinv, hs1, r1, N);
    k_lin1<<<nb3, 256, 0, stream>>>((const float4*)x, W1, dinv, hs1, r2, N);
  }

  int nb_g1 = (N * 8 + 255) / 256;  // 3125
  k_g1l2<<<nb_g1, 256, 0, stream>>>(rowptr, cntg, csr, hs1, dinv, b1, W2, hs2, N);

  int nb_g2 = (N * 4 + 255) / 256;  // 1563
  k_g2sm<<<nb_g2, 256, 0, stream>>>(rowptr, cntg, csr, hs2, dinv, b2,
                                    (float4*)out, N);
}

// Round 12
// 301.786 us; speedup vs baseline: 1.2240x; 1.2240x over previous
//
#include <hip/hip_runtime.h>
#include <math.h>

// Problem constants: N=100000, E=3200000, F=256, H=32, C=16
constexpr int Fdim = 256;
constexpr int Hdim = 32;
constexpr int Cdim = 16;
constexpr int EPB = 8192;   // edges per block in pass B
constexpr int MAXNB = 512;  // max coarse buckets (N <= 131072)

// ---- bf16 helpers (RNE) ----
__device__ inline unsigned bfpack2(float lo, float hi) {
  unsigned a = __builtin_bit_cast(unsigned, lo);
  unsigned b = __builtin_bit_cast(unsigned, hi);
  a += 0x7FFFu + ((a >> 16) & 1u);
  b += 0x7FFFu + ((b >> 16) & 1u);
  return (a >> 16) | (b & 0xFFFF0000u);
}
__device__ inline float4 bfunpack4(uint2 w) {
  float4 r;
  r.x = __builtin_bit_cast(float, w.x << 16);
  r.y = __builtin_bit_cast(float, w.x & 0xFFFF0000u);
  r.z = __builtin_bit_cast(float, w.y << 16);
  r.w = __builtin_bit_cast(float, w.y & 0xFFFF0000u);
  return r;
}

// ---- wave shuffle helpers ----
__device__ inline float4 shfl4(float4 v, int lane) {
  float4 r;
  r.x = __shfl(v.x, lane, 64);
  r.y = __shfl(v.y, lane, 64);
  r.z = __shfl(v.z, lane, 64);
  r.w = __shfl(v.w, lane, 64);
  return r;
}
__device__ inline float4 sel4(bool c, float4 a, float4 b) {
  float4 r;
  r.x = c ? a.x : b.x;
  r.y = c ? a.y : b.y;
  r.z = c ? a.z : b.z;
  r.w = c ? a.w : b.w;
  return r;
}

__global__ __launch_bounds__(256) void k_zero_int(int* __restrict__ p, int n) {
  int i = blockIdx.x * blockDim.x + threadIdx.x;
  if (i < n) p[i] = 0;
}

// ---------- Pass B: coarse-bin edges by dst>>8 into bucket-contiguous chunks.
__global__ __launch_bounds__(256) void k_binB(const int* __restrict__ src,
                                              const int* __restrict__ dst,
                                              int* __restrict__ bcur,
                                              unsigned* __restrict__ pairs,
                                              int e, int nb, int bcap) {
  __shared__ int hist[MAXNB];
  __shared__ int cbase[MAXNB];
  int lo = blockIdx.x * EPB;
  int hi = lo + EPB;
  if (hi > e) hi = e;
  for (int t = threadIdx.x; t < nb; t += 256) hist[t] = 0;
  __syncthreads();
  for (int i = lo + threadIdx.x; i < hi; i += 256) {
    atomicAdd(&hist[dst[i] >> 8], 1);
  }
  __syncthreads();
  for (int t = threadIdx.x; t < nb; t += 256) {
    int h = hist[t];
    int base = h ? atomicAdd(&bcur[t], h) : 0;
    cbase[t] = t * bcap + base;
    hist[t] = 0;  // reuse as local cursor
  }
  __syncthreads();
  for (int i = lo + threadIdx.x; i < hi; i += 256) {
    int d = dst[i];
    int bk = d >> 8;
    int o = atomicAdd(&hist[bk], 1);
    int idx = cbase[bk] + o;
    if (idx < (bk + 1) * bcap)  // statistical overflow guard
      pairs[idx] = ((unsigned)(d & 255) << 24) | (unsigned)src[i];
  }
}

// ---------- exclusive scan of bucket counts -> packed-CSR bucket bases ----------
__global__ __launch_bounds__(512) void k_scanb(const int* __restrict__ bcur,
                                               int* __restrict__ bbase,
                                               int nb, int bcap) {
  __shared__ int s[512];
  int t = threadIdx.x;
  int v = 0;
  if (t < nb) {
    v = bcur[t];
    if (v > bcap) v = bcap;
  }
  s[t] = v;
  __syncthreads();
  for (int off = 1; off < 512; off <<= 1) {
    int u = (t >= off) ? s[t - off] : 0;
    __syncthreads();
    s[t] += u;
    __syncthreads();
  }
  if (t < nb) bbase[t] = s[t] - v;  // exclusive
}

// ---------- Pass C: one block per bucket; LDS counters + LDS scan -> PACKED csr.
__global__ __launch_bounds__(256) void k_binC(const int* __restrict__ bcur,
                                              const int* __restrict__ bbase,
                                              const unsigned* __restrict__ pairs,
                                              int* __restrict__ csr,
                                              int* __restrict__ rowptr,
                                              int* __restrict__ cntg,
                                              float* __restrict__ dinv,
                                              int n, int bcap) {
  __shared__ int cnt2[256];
  __shared__ int loc0[256];
  __shared__ int cur2[256];
  int b = blockIdx.x;
  int tid = threadIdx.x;
  int nE = bcur[b];
  if (nE > bcap) nE = bcap;
  int base = b * bcap;
  cnt2[tid] = 0;
  __syncthreads();
  for (int i = tid; i < nE; i += 256) {
    atomicAdd(&cnt2[pairs[base + i] >> 24], 1);
  }
  __syncthreads();
  int c = cnt2[tid];
  loc0[tid] = c;
  __syncthreads();
  for (int off = 1; off < 256; off <<= 1) {
    int u = (tid >= off) ? loc0[tid - off] : 0;
    __syncthreads();
    loc0[tid] += u;
    __syncthreads();
  }
  int rowstart = bbase[b] + loc0[tid] - c;
  __syncthreads();
  loc0[tid] = rowstart;
  cur2[tid] = 0;
  int d = b * 256 + tid;
  if (d < n) {
    rowptr[d] = rowstart;
    cntg[d] = c;
    dinv[d] = 1.0f / sqrtf((float)(c + 1));  // +1 self-loop
  }
  __syncthreads();
  for (int i = tid; i < nE; i += 256) {
    unsigned w = pairs[base + i];
    int loc = (int)(w >> 24);
    int s = (int)(w & 0xFFFFFFu);
    int o = atomicAdd(&cur2[loc], 1);
    csr[loc0[loc] + o] = s;
  }
}

// ---------- hs1(bf16) = dinv * (x @ W1): coalesced shuffle-transpose loads.
// Per wave (64 rows): each K-step issues 4 phase-loads where lane l reads
// row r0+16p+(l>>2), chunk k0+(l&3) -> 16 fully-consumed 64B segments per
// instr (4x fewer scattered requests than row-per-lane). Redistribution to
// row-per-lane ownership: lane l pulls chunk cc from lane ((l&15)<<2)|cc of
// phase l>>4 (4 shfl4 + cndmask phase-select). W index stays wave-uniform
// -> scalar s_load path. fp32 accumulate, bf16 store.
__global__ __launch_bounds__(256) void k_lin1(const float4* __restrict__ x4,
                                              const float* __restrict__ W,
                                              const float* __restrict__ dinv,
                                              unsigned short* __restrict__ hs,
                                              int n) {
  int l = threadIdx.x & 63;
  int r0 = blockIdx.x * 256 + (threadIdx.x >> 6) * 64;  // wave row base
  int qrow = l >> 2;  // row-within-phase 0..15
  int cch = l & 3;    // chunk offset 0..3
  bool b0 = (l & 16) != 0;
  bool b1 = (l & 32) != 0;
  int srcbase = (l & 15) << 2;

  int rA = r0 + qrow;      if (rA >= n) rA = n - 1;
  int rB = r0 + 16 + qrow; if (rB >= n) rB = n - 1;
  int rC = r0 + 32 + qrow; if (rC >= n) rC = n - 1;
  int rD = r0 + 48 + qrow; if (rD >= n) rD = n - 1;
  const float4* pA = x4 + (size_t)rA * (Fdim / 4) + cch;
  const float4* pB = x4 + (size_t)rB * (Fdim / 4) + cch;
  const float4* pC = x4 + (size_t)rC * (Fdim / 4) + cch;
  const float4* pD = x4 + (size_t)rD * (Fdim / 4) + cch;

  float acc[Hdim];
#pragma unroll
  for (int c = 0; c < Hdim; ++c) acc[c] = 0.f;

#pragma unroll 2
  for (int t = 0; t < 16; ++t) {
    int k0 = t * 4;
    float4 v0 = pA[k0];
    float4 v1 = pB[k0];
    float4 v2 = pC[k0];
    float4 v3 = pD[k0];
#pragma unroll
    for (int cc = 0; cc < 4; ++cc) {
      int sl = srcbase | cc;
      float4 t0 = shfl4(v0, sl);
      float4 t1 = shfl4(v1, sl);
      float4 t2 = shfl4(v2, sl);
      float4 t3 = shfl4(v3, sl);
      float4 xlo = sel4(b0, t1, t0);
      float4 xhi = sel4(b0, t3, t2);
      float4 xv = sel4(b1, xhi, xlo);
      const float* wp = W + (k0 + cc) * 4 * Hdim;  // wave-uniform -> s_load
#pragma unroll
      for (int c = 0; c < Hdim; ++c) acc[c] = fmaf(xv.x, wp[c], acc[c]);
#pragma unroll
      for (int c = 0; c < Hdim; ++c) acc[c] = fmaf(xv.y, wp[Hdim + c], acc[c]);
#pragma unroll
      for (int c = 0; c < Hdim; ++c) acc[c] = fmaf(xv.z, wp[2 * Hdim + c], acc[c]);
#pragma unroll
      for (int c = 0; c < Hdim; ++c) acc[c] = fmaf(xv.w, wp[3 * Hdim + c], acc[c]);
    }
  }

  int r = r0 + l;
  if (r < n) {
    float di = dinv[r];
    uint4* hp = (uint4*)(hs + (size_t)r * Hdim);  // 64B row
#pragma unroll
    for (int q = 0; q < 4; ++q) {
      uint4 u;
      u.x = bfpack2(di * acc[8 * q + 0], di * acc[8 * q + 1]);
      u.y = bfpack2(di * acc[8 * q + 2], di * acc[8 * q + 3]);
      u.z = bfpack2(di * acc[8 * q + 4], di * acc[8 * q + 5]);
      u.w = bfpack2(di * acc[8 * q + 6], di * acc[8 * q + 7]);
      hp[q] = u;
    }
  }
}

// ---------- Fused gather1 + relu/bias + lin2: 8 lanes/row, bf16 rows ----------
__global__ __launch_bounds__(256) void k_g1l2(const int* __restrict__ rowptr,
                                              const int* __restrict__ cnt,
                                              const int* __restrict__ csr,
                                              const unsigned short* __restrict__ hs,
                                              const float* __restrict__ dinv,
                                              const float* __restrict__ b1,
                                              const float* __restrict__ W2,
                                              unsigned short* __restrict__ hs2, int n) {
  int t = blockIdx.x * blockDim.x + threadIdx.x;
  int d = t >> 3, f = t & 7;
  if (d >= n) return;
  int c = cnt[d];
  const int* row = csr + rowptr[d];
  float4 acc = bfunpack4(((const uint2*)(hs + (size_t)d * Hdim))[f]);
  int k = 0;
  for (; k + 3 < c; k += 4) {
    int s0 = row[k], s1 = row[k + 1], s2 = row[k + 2], s3 = row[k + 3];
    float4 v0 = bfunpack4(((const uint2*)(hs + (size_t)s0 * Hdim))[f]);
    float4 v1 = bfunpack4(((const uint2*)(hs + (size_t)s1 * Hdim))[f]);
    float4 v2 = bfunpack4(((const uint2*)(hs + (size_t)s2 * Hdim))[f]);
    float4 v3 = bfunpack4(((const uint2*)(hs + (size_t)s3 * Hdim))[f]);
    acc.x += (v0.x + v1.x) + (v2.x + v3.x);
    acc.y += (v0.y + v1.y) + (v2.y + v3.y);
    acc.z += (v0.z + v1.z) + (v2.z + v3.z);
    acc.w += (v0.w + v1.w) + (v2.w + v3.w);
  }
  for (; k < c; ++k) {
    float4 v = bfunpack4(((const uint2*)(hs + (size_t)row[k] * Hdim))[f]);
    acc.x += v.x; acc.y += v.y; acc.z += v.z; acc.w += v.w;
  }
  float di = dinv[d];
  float h[4];
  h[0] = fmaxf(fmaf(di, acc.x, b1[4 * f + 0]), 0.f);
  h[1] = fmaxf(fmaf(di, acc.y, b1[4 * f + 1]), 0.f);
  h[2] = fmaxf(fmaf(di, acc.z, b1[4 * f + 2]), 0.f);
  h[3] = fmaxf(fmaf(di, acc.w, b1[4 * f + 3]), 0.f);
  float p[Cdim];
#pragma unroll
  for (int j = 0; j < Cdim; ++j) p[j] = 0.f;
#pragma unroll
  for (int r = 0; r < 4; ++r) {
    const float* w = W2 + (4 * f + r) * Cdim;
#pragma unroll
    for (int j = 0; j < Cdim; ++j) p[j] = fmaf(h[r], w[j], p[j]);
  }
#pragma unroll
  for (int m = 1; m < 8; m <<= 1) {
#pragma unroll
    for (int j = 0; j < Cdim; ++j) p[j] += __shfl_xor(p[j], m, 64);
  }
  if (f < 4) {
    uint2 u;
    u.x = bfpack2(di * p[4 * f + 0], di * p[4 * f + 1]);
    u.y = bfpack2(di * p[4 * f + 2], di * p[4 * f + 3]);
    ((uint2*)(hs2 + (size_t)d * Cdim))[f] = u;  // 32B row
  }
}

// ---------- Fused gather2 + softmax: 4 lanes/row, bf16 rows ----------
__global__ __launch_bounds__(256) void k_g2sm(const int* __restrict__ rowptr,
                                              const int* __restrict__ cnt,
                                              const int* __restrict__ csr,
                                              const unsigned short* __restrict__ hs,
                                              const float* __restrict__ dinv,
                                              const float* __restrict__ b2,
                                              float4* __restrict__ out, int n) {
  int t = blockIdx.x * blockDim.x + threadIdx.x;
  int d = t >> 2, f = t & 3;
  if (d >= n) return;
  int c = cnt[d];
  const int* row = csr + rowptr[d];
  float4 acc = bfunpack4(((const uint2*)(hs + (size_t)d * Cdim))[f]);
  int k = 0;
  for (; k + 3 < c; k += 4) {
    int s0 = row[k], s1 = row[k + 1], s2 = row[k + 2], s3 = row[k + 3];
    float4 v0 = bfunpack4(((const uint2*)(hs + (size_t)s0 * Cdim))[f]);
    float4 v1 = bfunpack4(((const uint2*)(hs + (size_t)s1 * Cdim))[f]);
    float4 v2 = bfunpack4(((const uint2*)(hs + (size_t)s2 * Cdim))[f]);
    float4 v3 = bfunpack4(((const uint2*)(hs + (size_t)s3 * Cdim))[f]);
    acc.x += (v0.x + v1.x) + (v2.x + v3.x);
    acc.y += (v0.y + v1.y) + (v2.y + v3.y);
    acc.z += (v0.z + v1.z) + (v2.z + v3.z);
    acc.w += (v0.w + v1.w) + (v2.w + v3.w);
  }
  for (; k < c; ++k) {
    float4 v = bfunpack4(((const uint2*)(hs + (size_t)row[k] * Cdim))[f]);
    acc.x += v.x; acc.y += v.y; acc.z += v.z; acc.w += v.w;
  }
  float di = dinv[d];
  float v0 = fmaf(di, acc.x, b2[4 * f + 0]);
  float v1 = fmaf(di, acc.y, b2[4 * f + 1]);
  float v2 = fmaf(di, acc.z, b2[4 * f + 2]);
  float v3 = fmaf(di, acc.w, b2[4 * f + 3]);
  float m = fmaxf(fmaxf(v0, v1), fmaxf(v2, v3));
  m = fmaxf(m, __shfl_xor(m, 1, 64));
  m = fmaxf(m, __shfl_xor(m, 2, 64));
  float e0 = expf(v0 - m), e1 = expf(v1 - m), e2 = expf(v2 - m), e3 = expf(v3 - m);
  float s = e0 + e1 + e2 + e3;
  s += __shfl_xor(s, 1, 64);
  s += __shfl_xor(s, 2, 64);
  float inv = 1.f / s;
  float4 o;
  o.x = e0 * inv; o.y = e1 * inv; o.z = e2 * inv; o.w = e3 * inv;
  out[(size_t)d * 4 + f] = o;
}

extern "C" void kernel_launch(void* const* d_in, const int* in_sizes, int n_in,
                              void* d_out, int out_size, void* d_ws, size_t ws_size,
                              hipStream_t stream) {
  const float* x = (const float*)d_in[0];
  const int* ei = (const int*)d_in[1];
  const float* W1 = (const float*)d_in[2];
  const float* b1 = (const float*)d_in[3];
  const float* W2 = (const float*)d_in[4];
  const float* b2 = (const float*)d_in[5];
  float* out = (float*)d_out;

  const int N = in_sizes[0] / Fdim;  // 100000
  const int E = in_sizes[1] / 2;     // 3200000
  const int* srcp = ei;              // edge_index[0]
  const int* dstp = ei + E;          // edge_index[1]

  const int NB = (N + 255) >> 8;            // 391 coarse buckets
  const int mean = (E + NB - 1) / NB;       // ~8184 edges/bucket
  const int BCAP = mean + mean / 16 + 256;  // ~8.5 sigma slack

  // Workspace: bcur | bbase | dinv | cntg | rowptr | csr | region{pairs / hs1+hs2}
  char* ws = (char*)d_ws;
  int* bcur = (int*)ws;      ws += (size_t)MAXNB * 4;
  int* bbase = (int*)ws;     ws += (size_t)MAXNB * 4;
  float* dinv = (float*)ws;  ws += (size_t)N * 4;
  int* cntg = (int*)ws;      ws += (size_t)N * 4;
  int* rowptr = (int*)ws;    ws += (size_t)(N + 4) * 4;
  int* csr = (int*)ws;       ws += (size_t)E * 4;  // 12.8 MB packed
  char* region = ws;         // max(pairs ~14MB, hs1 6.4MB + hs2 3.2MB)
  unsigned* pairs = (unsigned*)region;            // dead after k_binC
  unsigned short* hs1 = (unsigned short*)region;  // aliases pairs
  unsigned short* hs2 = (unsigned short*)(region + (size_t)N * Hdim * 2);

  int nbB = (E + EPB - 1) / EPB;  // 391

  k_zero_int<<<(NB + 255) / 256, 256, 0, stream>>>(bcur, NB);
  k_binB<<<nbB, 256, 0, stream>>>(srcp, dstp, bcur, pairs, E, NB, BCAP);
  k_scanb<<<1, 512, 0, stream>>>(bcur, bbase, NB, BCAP);
  k_binC<<<NB, 256, 0, stream>>>(bcur, bbase, pairs, csr, rowptr, cntg, dinv, N, BCAP);

  int nb_l1 = (N + 255) / 256;  // 391, single dispatch
  k_lin1<<<nb_l1, 256, 0, stream>>>((const float4*)x, W1, dinv, hs1, N);

  int nb_g1 = (N * 8 + 255) / 256;  // 3125
  k_g1l2<<<nb_g1, 256, 0, stream>>>(rowptr, cntg, csr, hs1, dinv, b1, W2, hs2, N);

  int nb_g2 = (N * 4 + 255) / 256;  // 1563
  k_g2sm<<<nb_g2, 256, 0, stream>>>(rowptr, cntg, csr, hs2, dinv, b2,
                                    (float4*)out, N);
}